// Round 1
// 319.433 us; speedup vs baseline: 1.0472x; 1.0472x over previous
//
#include <hip/hip_runtime.h>
#include <stdint.h>

#define BTOT 32768
#define NIMG 16      // images per conv block
#define KF   416     // padded feature dim (400 real)

typedef __attribute__((ext_vector_type(8))) short short8;
typedef __attribute__((ext_vector_type(4))) float floatx4;

__device__ __forceinline__ unsigned short f2bf(float x) {
    union { float f; unsigned int u; } v; v.f = x;
    unsigned int r = v.u + 0x7fffu + ((v.u >> 16) & 1u);  // RNE
    return (unsigned short)(r >> 16);
}

// ---------------- conv(5x5,3->16) + bias + relu + 2x2 maxpool via MFMA implicit GEMM ----------
// M = output positions ordered m = quad*4 + corner  (so D rows (lane>>4)*4+reg = one pool quad
// in one lane's 4 acc regs -> in-lane maxpool), N = 16 co, K = 3 x 32 (25 taps + 7 zero-weight).
// Wave handles 4 images = 100 positions = 25 exact 16x16 tiles. Weights stay in 12 VGPRs.
__global__ __launch_bounds__(256) void conv_pool_kernel(
    const float* __restrict__ fm, const float* __restrict__ cw,
    const float* __restrict__ cb, unsigned short* __restrict__ feat)
{
    __shared__ __align__(16) unsigned short s_img[NIMG * 588];   // bf16 images, 18816 B
    __shared__ __align__(16) unsigned short s_out[NIMG * 416];   // pooled feats + pad, 13312 B

    const int tid  = threadIdx.x;
    const int b0   = blockIdx.x * NIMG;
    const int lane = tid & 63;
    const int wave = tid >> 6;

    // stage 16 images fp32 -> bf16, layout-preserving flat copy
    const float4* in4 = (const float4*)(fm + (size_t)b0 * 588);
    for (int idx = tid; idx < NIMG * 147; idx += 256) {
        float4 v = in4[idx];
        unsigned int u0 = (unsigned int)f2bf(v.x) | ((unsigned int)f2bf(v.y) << 16);
        unsigned int u1 = (unsigned int)f2bf(v.z) | ((unsigned int)f2bf(v.w) << 16);
        *(uint2*)&s_img[idx * 4] = make_uint2(u0, u1);
    }
    // zero the feature pad region [400..416) per image
    {
        int img = tid >> 4, k = tid & 15;
        s_out[img * 416 + 400 + k] = 0;
    }

    const int co = lane & 15;    // B col / D col
    const int q  = lane >> 4;    // k-chunk (A/B), quad-in-tile (D)

    // B fragments (weights): col = co, k = 8q+j, taps t>=25 are ZERO (kills A garbage)
    union U8 { unsigned short h[8]; short8 v; };
    U8 bw[3];
    #pragma unroll
    for (int ci = 0; ci < 3; ++ci) {
        #pragma unroll
        for (int j = 0; j < 8; ++j) {
            int t = q * 8 + j;
            bw[ci].h[j] = (t < 25) ? f2bf(cw[co * 75 + ci * 25 + t]) : (unsigned short)0;
        }
    }
    const float bias = cb[co];

    // per-lane A-gather tap offsets (half units), fixed for the whole kernel
    int hoff[8];
    #pragma unroll
    for (int j = 0; j < 8; ++j) {
        int t = q * 8 + j;
        int kh = t / 5;
        hoff[j] = (t < 25) ? (kh * 14 + (t - kh * 5)) : 0;
    }

    // A-side per-lane constants: row r covers m = 16t + r
    const int r  = lane & 15;
    const int qd = r >> 2;          // quad within tile
    const int cy = (r >> 1) & 1;    // pool corner y
    const int cx = r & 1;           // pool corner x

    __syncthreads();

    const unsigned short* sw = s_img + wave * 4 * 588;
    unsigned short* ow = s_out + wave * 4 * 416;

    for (int t = 0; t < 25; ++t) {
        // A gather: global quad g in [0,100)
        int g   = t * 4 + qd;
        int img = (g * 41) >> 10;           // g / 25   (valid for g < 128)
        int q25 = g - img * 25;
        int qy  = (q25 * 13) >> 6;          // q25 / 5  (valid for q25 < 25)
        int qx  = q25 - qy * 5;
        const unsigned short* p = sw + img * 588 + (qy * 2 + cy) * 14 + (qx * 2 + cx);

        floatx4 acc = {0.f, 0.f, 0.f, 0.f};
        #pragma unroll
        for (int ci = 0; ci < 3; ++ci) {
            union { unsigned int u[4]; short8 v; } a;
            #pragma unroll
            for (int pp = 0; pp < 4; ++pp) {
                unsigned int lo = p[ci * 196 + hoff[2 * pp]];       // ds_read_u16, ci*392B folds
                unsigned int hi = p[ci * 196 + hoff[2 * pp + 1]];   // into the ds offset imm
                a.u[pp] = lo | (hi << 16);
            }
            acc = __builtin_amdgcn_mfma_f32_16x16x32_bf16(a.v, bw[ci].v, acc, 0, 0, 0);
        }

        // D: lane holds quad (lane>>4) corners in acc[0..3], col = co -> in-lane 2x2 pool
        int gd   = t * 4 + q;
        int imgd = (gd * 41) >> 10;
        int q25d = gd - imgd * 25;
        float m = fmaxf(fmaxf(acc[0], acc[1]), fmaxf(acc[2], acc[3])) + bias;
        ow[imgd * 416 + co * 25 + q25d] = f2bf(fmaxf(m, 0.f));
    }

    __syncthreads();
    // coalesced copy-out: 16 images x 416 halves (pad already zeroed)
    const uint4* so4 = (const uint4*)s_out;
    uint4* fo4 = (uint4*)(feat + (size_t)b0 * KF);
    for (int idx = tid; idx < NIMG * 52; idx += 256)
        fo4[idx] = so4[idx];
}

// ---------------- lin_w [1000][400] fp32 -> Wb [1024][416] bf16 (zero padded) ----------------
__global__ __launch_bounds__(256) void prep_w_kernel(const float* __restrict__ lw,
                                                     unsigned short* __restrict__ Wb)
{
    int c = blockIdx.x * 256 + threadIdx.x;   // one 8-element chunk
    if (c >= 1024 * 52) return;
    int n = c / 52;
    int kc = (c - n * 52) * 8;
    unsigned short v[8];
    #pragma unroll
    for (int j = 0; j < 8; ++j) {
        int k = kc + j;
        float x = (n < 1000 && k < 400) ? lw[n * 400 + k] : 0.f;
        v[j] = f2bf(x);
    }
    *(uint4*)(Wb + (size_t)n * KF + kc) = *(uint4*)v;
}

// ---------------- GEMM: out[32768][1000] = F[32768][416] @ Wb[1024][416]^T + lin_b ----------------
// m97 pattern: global_load_lds width=16 staging (dest = wave-uniform base + lane*16).
__global__ __launch_bounds__(256) void gemm_kernel(
    const unsigned short* __restrict__ F, const unsigned short* __restrict__ Wb,
    const float* __restrict__ lb, float* __restrict__ out)
{
    __shared__ __align__(16) unsigned short At[128 * 32];
    __shared__ __align__(16) unsigned short Bt[128 * 32];

    const int tid = threadIdx.x;
    const int bm = blockIdx.x >> 3;
    const int bn = blockIdx.x & 7;
    const int m0 = bm * 128;
    const int n0 = bn * 128;

    const int w = tid >> 6;
    const int lane = tid & 63;
    const int wm = w & 1, wn = w >> 1;     // 2x2 wave grid, each wave 64x64
    const int lq = lane >> 4, ln = lane & 15;

    floatx4 zero = {0.f, 0.f, 0.f, 0.f};
    floatx4 acc[4][4];
    #pragma unroll
    for (int i = 0; i < 4; ++i)
        #pragma unroll
        for (int j = 0; j < 4; ++j) acc[i][j] = zero;

    // staging: wave w covers rows [w*16, w*16+16) (+64 for t=1); lane L -> row w*16+(L>>2), chunk L&3
    const int srow = w * 16 + (lane >> 2);
    const int skc = (lane & 3) * 8;
    const unsigned short* gA = F + (size_t)(m0 + srow) * KF + skc;
    const unsigned short* gB = Wb + (size_t)(n0 + srow) * KF + skc;

    for (int kb = 0; kb < KF; kb += 32) {
        #pragma unroll
        for (int t = 0; t < 2; ++t) {
            __builtin_amdgcn_global_load_lds(
                (const __attribute__((address_space(1))) void*)(gA + (size_t)(t * 64) * KF + kb),
                (__attribute__((address_space(3))) void*)&At[(w * 16 + t * 64) * 32],
                16, 0, 0);
            __builtin_amdgcn_global_load_lds(
                (const __attribute__((address_space(1))) void*)(gB + (size_t)(t * 64) * KF + kb),
                (__attribute__((address_space(3))) void*)&Bt[(w * 16 + t * 64) * 32],
                16, 0, 0);
        }
        __syncthreads();
        short8 af[4], bf[4];
        #pragma unroll
        for (int i = 0; i < 4; ++i)
            af[i] = *(const short8*)&At[(wm * 64 + i * 16 + ln) * 32 + lq * 8];
        #pragma unroll
        for (int j = 0; j < 4; ++j)
            bf[j] = *(const short8*)&Bt[(wn * 64 + j * 16 + ln) * 32 + lq * 8];
        #pragma unroll
        for (int i = 0; i < 4; ++i)
            #pragma unroll
            for (int j = 0; j < 4; ++j)
                acc[i][j] = __builtin_amdgcn_mfma_f32_16x16x32_bf16(af[i], bf[j], acc[i][j], 0, 0, 0);
        __syncthreads();
    }

    #pragma unroll
    for (int j = 0; j < 4; ++j) {
        int n = n0 + wn * 64 + j * 16 + ln;
        if (n >= 1000) continue;           // padded N region
        float bias = lb[n];
        #pragma unroll
        for (int i = 0; i < 4; ++i) {
            int mb = m0 + wm * 64 + i * 16 + lq * 4;   // C/D: col=lane&15, row=quad*4+reg (m89/m91)
            #pragma unroll
            for (int rr = 0; rr < 4; ++rr)
                out[(size_t)(mb + rr) * 1000 + n] = acc[i][j][rr] + bias;
        }
    }
}

extern "C" void kernel_launch(void* const* d_in, const int* in_sizes, int n_in,
                              void* d_out, int out_size, void* d_ws, size_t ws_size,
                              hipStream_t stream)
{
    const float* fm = (const float*)d_in[0];   // (32768,3,14,14)
    const float* cw = (const float*)d_in[1];   // (16,3,5,5)
    const float* cb = (const float*)d_in[2];   // (16,)
    const float* lw = (const float*)d_in[3];   // (1000,400)
    const float* lb = (const float*)d_in[4];   // (1000,)
    float* out = (float*)d_out;                // (32768,1000) fp32

    unsigned short* feat = (unsigned short*)d_ws;                        // [32768][416] bf16
    unsigned short* Wb   = (unsigned short*)d_ws + (size_t)BTOT * KF;    // [1024][416] bf16

    prep_w_kernel<<<208, 256, 0, stream>>>(lw, Wb);
    conv_pool_kernel<<<BTOT / NIMG, 256, 0, stream>>>(fm, cw, cb, feat);
    gemm_kernel<<<2048, 256, 0, stream>>>(feat, Wb, lb, out);
}

// Round 2
// 302.510 us; speedup vs baseline: 1.1058x; 1.0559x over previous
//
#include <hip/hip_runtime.h>
#include <stdint.h>

#define BTOT 32768
#define NIMG 16      // images per conv block
#define KF   416     // padded feature dim (400 real)

typedef __attribute__((ext_vector_type(8))) short short8;
typedef __attribute__((ext_vector_type(4))) float floatx4;

__device__ __forceinline__ unsigned short f2bf(float x) {
    union { float f; unsigned int u; } v; v.f = x;
    unsigned int r = v.u + 0x7fffu + ((v.u >> 16) & 1u);  // RNE
    return (unsigned short)(r >> 16);
}

// ---------------- conv(5x5,3->16) + bias + relu + 2x2 maxpool via MFMA implicit GEMM ----------
// M = positions (m = quad*4 + corner -> in-lane 2x2 pool in D), N = 16 co.
// K re-permuted: chunk c = (ci,row) holds taps row*5..row*5+4 (+3 zero slots); 16 chunks
// (15 real + 1 dead) = 4 MFMAs of K=32. Lane chunk = row-contiguous halves -> 2 DS instrs
// (ds_read2_b32 + ds_read_b32) instead of 8 ds_read_u16; odd-column start via v_alignbit(cx*16).
__global__ __launch_bounds__(256) void conv_pool_kernel(
    const float* __restrict__ fm, const float* __restrict__ cw,
    const float* __restrict__ cb, unsigned short* __restrict__ feat,
    const float* __restrict__ lw, unsigned short* __restrict__ Wb)
{
    // -------- folded prep_w path (blocks 2048..2255) --------
    if (blockIdx.x >= BTOT / NIMG) {
        int c = (blockIdx.x - BTOT / NIMG) * 256 + threadIdx.x;   // one 8-element chunk
        if (c < 1024 * 52) {
            int n = c / 52;
            int kc = (c - n * 52) * 8;
            unsigned short v[8];
            #pragma unroll
            for (int j = 0; j < 8; ++j) {
                int k = kc + j;
                float x = (n < 1000 && k < 400) ? lw[n * 400 + k] : 0.f;
                v[j] = f2bf(x);
            }
            *(uint4*)(Wb + (size_t)n * KF + kc) = *(uint4*)v;
        }
        return;
    }

    __shared__ __align__(16) unsigned short s_img[NIMG * 588];   // bf16 images, 18816 B
    __shared__ __align__(16) unsigned short s_out[NIMG * 416];   // pooled feats + pad, 13312 B

    const int tid  = threadIdx.x;
    const int b0   = blockIdx.x * NIMG;
    const int lane = tid & 63;
    const int wave = tid >> 6;

    // stage 16 images fp32 -> bf16, b128 LDS writes (1176 uint4)
    const float4* in4 = (const float4*)(fm + (size_t)b0 * 588);
    for (int idx = tid; idx < NIMG * 147 / 2; idx += 256) {
        float4 v0 = in4[2 * idx], v1 = in4[2 * idx + 1];
        uint4 u;
        u.x = (unsigned int)f2bf(v0.x) | ((unsigned int)f2bf(v0.y) << 16);
        u.y = (unsigned int)f2bf(v0.z) | ((unsigned int)f2bf(v0.w) << 16);
        u.z = (unsigned int)f2bf(v1.x) | ((unsigned int)f2bf(v1.y) << 16);
        u.w = (unsigned int)f2bf(v1.z) | ((unsigned int)f2bf(v1.w) << 16);
        *(uint4*)&s_img[idx * 8] = u;
    }
    // zero the feature pad region [400..416) per image
    {
        int img = tid >> 4, k = tid & 15;
        s_out[img * 416 + 400 + k] = 0;
    }

    const int co = lane & 15;       // B col / D col
    const int q  = lane >> 4;       // k-chunk select (A/B), quad-in-tile (D)
    const int r  = lane & 15;       // A row (M within tile)
    const int qd = r >> 2;          // quad within tile
    const int cy = (r >> 1) & 1;    // pool corner y
    const int cx = r & 1;           // pool corner x
    const int sh = cx << 4;         // alignbit shift for odd column start

    // weights per chunk c = 4i+q: (ci,row) = (c/5, c%5) for c<15; c==15 dead (all-zero)
    union U8 { unsigned short h[8]; short8 v; };
    U8 bw[4];
    int chunkdw[4];                 // dword offset of chunk row within image: ci*98 + row*7
    #pragma unroll
    for (int i = 0; i < 4; ++i) {
        int c = 4 * i + q;
        int ci = (c < 15) ? (c / 5) : 0;
        int row = (c < 15) ? (c - ci * 5) : 0;
        chunkdw[i] = ci * 98 + row * 7;
        #pragma unroll
        for (int j = 0; j < 8; ++j)
            bw[i].h[j] = (c < 15 && j < 5) ? f2bf(cw[co * 75 + ci * 25 + row * 5 + j])
                                           : (unsigned short)0;
    }
    const float bias = cb[co];

    __syncthreads();

    const unsigned int* sw32 = (const unsigned int*)s_img + wave * 1176;  // 4 images/wave
    unsigned short* ow = s_out + wave * 4 * 416;

    for (int t = 0; t < 25; ++t) {
        // window base for this lane's A row: global quad g, image-local quad (qy,qx)
        int g   = t * 4 + qd;
        int img = (g * 41) >> 10;           // g / 25   (g < 128)
        int q25 = g - img * 25;
        int qy  = (q25 * 13) >> 6;          // q25 / 5  (q25 < 25)
        int qx  = q25 - qy * 5;
        int wb  = img * 294 + (qy * 2 + cy) * 7 + qx;   // dword offset, cx folded into sh

        floatx4 acc = {0.f, 0.f, 0.f, 0.f};
        #pragma unroll
        for (int i = 0; i < 4; ++i) {
            const unsigned int* p = sw32 + wb + chunkdw[i];
            unsigned int d0 = p[0], d1 = p[1], d2 = p[2];   // halves 0..5 of the row
            union { unsigned int u[4]; short8 v; } a;
            a.u[0] = __builtin_amdgcn_alignbit(d1, d0, sh); // taps c0,c1
            a.u[1] = __builtin_amdgcn_alignbit(d2, d1, sh); // taps c2,c3
            a.u[2] = __builtin_amdgcn_alignbit(d2, d2, sh); // tap c4 (+garbage, weight 0)
            a.u[3] = 0;                                     // slots 6,7 dead
            acc = __builtin_amdgcn_mfma_f32_16x16x32_bf16(a.v, bw[i].v, acc, 0, 0, 0);
        }

        // D: lane holds quad (lane>>4) corners in acc[0..3], col = co -> in-lane 2x2 pool
        int gd   = t * 4 + q;
        int imgd = (gd * 41) >> 10;
        int q25d = gd - imgd * 25;
        float m = fmaxf(fmaxf(acc[0], acc[1]), fmaxf(acc[2], acc[3])) + bias;
        ow[imgd * 416 + co * 25 + q25d] = f2bf(fmaxf(m, 0.f));
    }

    __syncthreads();
    // coalesced copy-out: 16 images x 416 halves (pad already zeroed)
    const uint4* so4 = (const uint4*)s_out;
    uint4* fo4 = (uint4*)(feat + (size_t)b0 * KF);
    for (int idx = tid; idx < NIMG * 52; idx += 256)
        fo4[idx] = so4[idx];
}

// ---------------- GEMM: out[32768][1000] = F[32768][416] @ Wb[1024][416]^T + lin_b ----------------
// m97 pattern: global_load_lds width=16 staging (dest = wave-uniform base + lane*16).
__global__ __launch_bounds__(256) void gemm_kernel(
    const unsigned short* __restrict__ F, const unsigned short* __restrict__ Wb,
    const float* __restrict__ lb, float* __restrict__ out)
{
    __shared__ __align__(16) unsigned short At[128 * 32];
    __shared__ __align__(16) unsigned short Bt[128 * 32];

    const int tid = threadIdx.x;
    const int bm = blockIdx.x >> 3;
    const int bn = blockIdx.x & 7;
    const int m0 = bm * 128;
    const int n0 = bn * 128;

    const int w = tid >> 6;
    const int lane = tid & 63;
    const int wm = w & 1, wn = w >> 1;     // 2x2 wave grid, each wave 64x64
    const int lq = lane >> 4, ln = lane & 15;

    floatx4 zero = {0.f, 0.f, 0.f, 0.f};
    floatx4 acc[4][4];
    #pragma unroll
    for (int i = 0; i < 4; ++i)
        #pragma unroll
        for (int j = 0; j < 4; ++j) acc[i][j] = zero;

    // staging: wave w covers rows [w*16, w*16+16) (+64 for t=1); lane L -> row w*16+(L>>2), chunk L&3
    const int srow = w * 16 + (lane >> 2);
    const int skc = (lane & 3) * 8;
    const unsigned short* gA = F + (size_t)(m0 + srow) * KF + skc;
    const unsigned short* gB = Wb + (size_t)(n0 + srow) * KF + skc;

    for (int kb = 0; kb < KF; kb += 32) {
        #pragma unroll
        for (int t = 0; t < 2; ++t) {
            __builtin_amdgcn_global_load_lds(
                (const __attribute__((address_space(1))) void*)(gA + (size_t)(t * 64) * KF + kb),
                (__attribute__((address_space(3))) void*)&At[(w * 16 + t * 64) * 32],
                16, 0, 0);
            __builtin_amdgcn_global_load_lds(
                (const __attribute__((address_space(1))) void*)(gB + (size_t)(t * 64) * KF + kb),
                (__attribute__((address_space(3))) void*)&Bt[(w * 16 + t * 64) * 32],
                16, 0, 0);
        }
        __syncthreads();
        short8 af[4], bf[4];
        #pragma unroll
        for (int i = 0; i < 4; ++i)
            af[i] = *(const short8*)&At[(wm * 64 + i * 16 + ln) * 32 + lq * 8];
        #pragma unroll
        for (int j = 0; j < 4; ++j)
            bf[j] = *(const short8*)&Bt[(wn * 64 + j * 16 + ln) * 32 + lq * 8];
        #pragma unroll
        for (int i = 0; i < 4; ++i)
            #pragma unroll
            for (int j = 0; j < 4; ++j)
                acc[i][j] = __builtin_amdgcn_mfma_f32_16x16x32_bf16(af[i], bf[j], acc[i][j], 0, 0, 0);
        __syncthreads();
    }

    #pragma unroll
    for (int j = 0; j < 4; ++j) {
        int n = n0 + wn * 64 + j * 16 + ln;
        if (n >= 1000) continue;           // padded N region
        float bias = lb[n];
        #pragma unroll
        for (int i = 0; i < 4; ++i) {
            int mb = m0 + wm * 64 + i * 16 + lq * 4;   // C/D: col=lane&15, row=quad*4+reg (m89/m91)
            #pragma unroll
            for (int rr = 0; rr < 4; ++rr)
                out[(size_t)(mb + rr) * 1000 + n] = acc[i][j][rr] + bias;
        }
    }
}

extern "C" void kernel_launch(void* const* d_in, const int* in_sizes, int n_in,
                              void* d_out, int out_size, void* d_ws, size_t ws_size,
                              hipStream_t stream)
{
    const float* fm = (const float*)d_in[0];   // (32768,3,14,14)
    const float* cw = (const float*)d_in[1];   // (16,3,5,5)
    const float* cb = (const float*)d_in[2];   // (16,)
    const float* lw = (const float*)d_in[3];   // (1000,400)
    const float* lb = (const float*)d_in[4];   // (1000,)
    float* out = (float*)d_out;                // (32768,1000) fp32

    unsigned short* feat = (unsigned short*)d_ws;                        // [32768][416] bf16
    unsigned short* Wb   = (unsigned short*)d_ws + (size_t)BTOT * KF;    // [1024][416] bf16

    // conv blocks [0,2048) + folded prep_w blocks [2048,2256)
    conv_pool_kernel<<<BTOT / NIMG + 208, 256, 0, stream>>>(fm, cw, cb, feat, lw, Wb);
    gemm_kernel<<<2048, 256, 0, stream>>>(feat, Wb, lb, out);
}